// Round 5
// baseline (88.054 us; speedup 1.0000x reference)
//
#include <hip/hip_runtime.h>

typedef __attribute__((ext_vector_type(8))) short bf16x8;
typedef __attribute__((ext_vector_type(4))) float f32x4;

#define MFMA16(A, Bv, C) __builtin_amdgcn_mfma_f32_16x16x32_bf16((A), (Bv), (C), 0, 0, 0)
#define WAITVM(N) asm volatile("s_waitcnt vmcnt(" #N ")" ::: "memory")

static constexpr int NB = 4, NS = 4096, ND = 1024, NH = 64;

__device__ __forceinline__ unsigned short f2bf(float f) {
    union { float f; unsigned int u; } x; x.f = f;
    unsigned int r = x.u + 0x7fffu + ((x.u >> 16) & 1u);
    return (unsigned short)(r >> 16);
}

// async global->LDS, 16B per lane; LDS dest = wave-uniform base + lane*16
__device__ __forceinline__ void gload_lds16(const void* g, void* l) {
    __builtin_amdgcn_global_load_lds((const __attribute__((address_space(1))) void*)g,
                                     (__attribute__((address_space(3))) void*)l, 16, 0, 0);
}

// ---------------------------------------------------------------------------
// Kernel 0: W[D][H] fp32 -> wT[m*64+n][k] bf16  (192 x 1024, 384 KB, L2-hot)
// ---------------------------------------------------------------------------
__global__ __launch_bounds__(256) void wconv(
    const float* __restrict__ Wq, const float* __restrict__ Wk,
    const float* __restrict__ Wv, unsigned short* __restrict__ wT)
{
    int mn = blockIdx.x;                 // 0..191 = m*64 + n
    int m = mn >> 6, n = mn & 63;
    const float* W = (m == 0) ? Wq : (m == 1) ? Wk : Wv;
    unsigned short* dst = wT + (size_t)mn * ND;
    for (int k = threadIdx.x; k < ND; k += 256)
        dst[k] = f2bf(W[(size_t)k * NH + n]);
}

// ---------------------------------------------------------------------------
// Kernel 1: QKV projection. Block = 32 rows, 512 blocks (2/CU).
// Ring-4 LDS staging (wT 12KB + x 4KB per slot), depth-3 prefetch, counted
// vmcnt (m201 protocol): s_waitcnt vmcnt(8) -> s_barrier -> stage(t+3) ->
// compute(t). Loads stay in flight across barriers; never drain to 0 in
// steady state. All VMEM is global_load_lds so vmcnt counting is exact
// (4 instrs/wave/step: 3 wT + 1 x).
// ---------------------------------------------------------------------------
__global__ __launch_bounds__(256) void qkv_proj(
    const float* __restrict__ x, const unsigned short* __restrict__ wT,
    unsigned short* __restrict__ qo, unsigned short* __restrict__ ko,
    unsigned short* __restrict__ vt)
{
    __shared__ unsigned short Ws[4][192][32];   // [slot][n-row][k], row = 64B
    __shared__ float Xs[4][32][32];             // [slot][row][k-float], row = 128B
    __shared__ unsigned short Ls[32][72];       // v transpose staging

    const int tid  = threadIdx.x;
    const int lane = tid & 63;
    const int w    = tid >> 6;
    const int lr   = lane & 15;
    const int lg   = lane >> 4;
    const int rf   = w & 1;                     // row-frag
    const int cg   = w >> 1;                    // col half
    const int mbase = blockIdx.x * 32;

    // wT stage: 1 instr = 16 rows x 64B; lane -> row lane>>2, 16B-chunk lane&3
    const int srow = lane >> 2;
    const int schk = (lane & 3) ^ (srow & 3);              // pre-swizzled source chunk
    // x stage: 1 instr = 8 rows x 128B; lane -> row lane>>3, 16B-chunk lane&7
    const int xrow = lane >> 3;
    const int xchk = (lane & 7) ^ ((xrow & 3) << 1);       // 32B-granule XOR swizzle

    f32x4 acc[6];                               // [m*2+fi]
    #pragma unroll
    for (int i = 0; i < 6; ++i) acc[i] = (f32x4){0.f, 0.f, 0.f, 0.f};

    #define STAGE(slot, kt)                                                          \
        do {                                                                         \
            _Pragma("unroll")                                                        \
            for (int i_ = 0; i_ < 3; ++i_) {                                         \
                int rbase_ = w * 48 + i_ * 16;                                       \
                const unsigned short* src_ =                                         \
                    wT + (size_t)(rbase_ + srow) * ND + (kt) * 32 + schk * 8;        \
                gload_lds16(src_, &Ws[slot][rbase_][0]);                             \
            }                                                                        \
            {                                                                        \
                const float* xsrc_ =                                                 \
                    x + (size_t)(mbase + w * 8 + xrow) * ND + (kt) * 32 + xchk * 4;  \
                gload_lds16(xsrc_, &Xs[slot][w * 8][0]);                             \
            }                                                                        \
        } while (0)

    // prologue: prefetch steps 0,1,2
    STAGE(0, 0);
    STAGE(1, 1);
    STAGE(2, 2);

    const int xg = (lg ^ (lr & 3)) * 8;         // swizzled float offset for x read
    for (int kt = 0; kt < 32; ++kt) {
        __builtin_amdgcn_sched_barrier(0);
        if (kt < 30)       WAITVM(8);
        else if (kt == 30) WAITVM(4);
        else               WAITVM(0);
        __builtin_amdgcn_s_barrier();
        __builtin_amdgcn_sched_barrier(0);
        if (kt + 3 < 32) STAGE((kt + 3) & 3, kt + 3);

        const int slot = kt & 3;
        float4 u0 = *(const float4*)&Xs[slot][rf * 16 + lr][xg];
        float4 u1 = *(const float4*)&Xs[slot][rf * 16 + lr][xg + 4];
        bf16x8 a;
        a[0] = (short)f2bf(u0.x); a[1] = (short)f2bf(u0.y);
        a[2] = (short)f2bf(u0.z); a[3] = (short)f2bf(u0.w);
        a[4] = (short)f2bf(u1.x); a[5] = (short)f2bf(u1.y);
        a[6] = (short)f2bf(u1.z); a[7] = (short)f2bf(u1.w);

        #pragma unroll
        for (int m = 0; m < 3; ++m)
            #pragma unroll
            for (int fi = 0; fi < 2; ++fi) {
                int row = m * 64 + (cg * 2 + fi) * 16 + lr;
                bf16x8 bfr = *(const bf16x8*)&Ws[slot][row][((lg ^ (lr & 3))) * 8];
                acc[m * 2 + fi] = MFMA16(a, bfr, acc[m * 2 + fi]);
            }
    }

    // epilogue: q (scaled), k row-major; v -> LDS -> transposed vT[b][h][s]
    #pragma unroll
    for (int fi = 0; fi < 2; ++fi)
        #pragma unroll
        for (int r = 0; r < 4; ++r) {
            int srw = lg * 4 + r;                 // C/D: row=(lane>>4)*4+reg
            int col = (cg * 2 + fi) * 16 + lr;    //      col=lane&15
            size_t grow = (size_t)(mbase + rf * 16 + srw);
            qo[grow * NH + col] = f2bf(acc[fi][r] * 0.125f);
            ko[grow * NH + col] = f2bf(acc[2 + fi][r]);
            Ls[rf * 16 + srw][col] = f2bf(acc[4 + fi][r]);
        }
    __syncthreads();
    {   // transpose 32 s x 64 h: thread -> (h, 8-s strip)
        int h  = tid >> 2;
        int so = (tid & 3) * 8;
        unsigned short tmp[8];
        #pragma unroll
        for (int jj = 0; jj < 8; ++jj) tmp[jj] = Ls[so + jj][h];
        int b_ = mbase >> 12;
        int sb = (mbase & (NS - 1)) + so;
        unsigned short* dst = vt + ((size_t)(b_ * NH + h)) * NS + sb;
        bf16x8 v0;
        #pragma unroll
        for (int jj = 0; jj < 8; ++jj) v0[jj] = (short)tmp[jj];
        *(bf16x8*)dst = v0;
    }
    #undef STAGE
}

// ---------------------------------------------------------------------------
// Kernel 2: attention phase A (flash-decode, chunked), ring-4 + counted vmcnt.
// Unit = (batch b, 64-q-row block j, kv-chunk c of 8 tiles = 512 kv).
// Per wave per step: 4 gload_lds (waves 0,1 stage K; waves 2,3 stage V).
// ---------------------------------------------------------------------------
__global__ __launch_bounds__(256) void attn_part(
    const unsigned short* __restrict__ q, const unsigned short* __restrict__ k,
    const unsigned short* __restrict__ vt, float* __restrict__ pO,
    float* __restrict__ pm, float* __restrict__ pl)
{
    __shared__ unsigned short Kt[4][64][64];   // [slot][kv][d], swizzled chunks
    __shared__ unsigned short Vt[4][64][64];   // [slot][h][kv], swizzled chunks
    __shared__ unsigned short Ps[4][16][72];

    const int bid = blockIdx.x;
    const int b = bid & 3;
    const int j = (bid >> 2) & 63;
    const int c = bid >> 8;                    // 0..7
    if (c > (j >> 3)) return;                  // dead block (beyond causal extent)
    const int ntile = (j + 1 - c * 8 < 8) ? (j + 1 - c * 8) : 8;
    const int tg0 = c * 8;

    const int tid  = threadIdx.x;
    const int lane = tid & 63;
    const int w    = tid >> 6;
    const int lr   = lane & 15;
    const int lg   = lane >> 4;
    const size_t bq = (size_t)b * NS;
    const int qb = j * 64;

    // stage lane mapping: 1 instr = 8 rows x 128B; lane -> row lane>>3, chunk lane&7
    const int srow = lane >> 3;
    const int schk = (lane & 7) ^ srow;        // pre-swizzled source chunk

    #define STAGEKV(slot, tg)                                                         \
        do {                                                                          \
            int kvb_ = (tg) * 64;                                                     \
            if (w < 2) {                                                              \
                _Pragma("unroll")                                                     \
                for (int i_ = 0; i_ < 4; ++i_) {                                      \
                    int rb_ = w * 32 + i_ * 8;                                        \
                    const unsigned short* src_ =                                      \
                        k + (bq + kvb_ + rb_ + srow) * NH + schk * 8;                 \
                    gload_lds16(src_, &Kt[slot][rb_][0]);                             \
                }                                                                     \
            } else {                                                                  \
                _Pragma("unroll")                                                     \
                for (int i_ = 0; i_ < 4; ++i_) {                                      \
                    int rb_ = (w - 2) * 32 + i_ * 8;                                  \
                    const unsigned short* src_ =                                      \
                        vt + ((size_t)(b * NH + rb_ + srow)) * NS + kvb_ + schk * 8;  \
                    gload_lds16(src_, &Vt[slot][rb_][0]);                             \
                }                                                                     \
            }                                                                         \
        } while (0)

    // Q frags (16 rows per wave)
    bf16x8 qf0, qf1;
    {
        const unsigned short* qp = q + (bq + qb + w * 16 + lr) * NH + lg * 8;
        qf0 = *(const bf16x8*)qp;
        qf1 = *(const bf16x8*)(qp + 32);
    }

    f32x4 O[4];
    #pragma unroll
    for (int i = 0; i < 4; ++i) O[i] = (f32x4){0.f, 0.f, 0.f, 0.f};
    float mrow[4], lsum[4];
    #pragma unroll
    for (int r = 0; r < 4; ++r) { mrow[r] = -3.0e38f; lsum[r] = 0.f; }

    // prologue: prefetch up to 3 tiles
    STAGEKV(0, tg0);
    if (ntile > 1) STAGEKV(1, tg0 + 1);
    if (ntile > 2) STAGEKV(2, tg0 + 2);

    for (int t = 0; t < ntile; ++t) {
        const int tg = tg0 + t;
        __builtin_amdgcn_sched_barrier(0);
        {
            const int rem = ntile - 1 - t;
            if (rem >= 2)      WAITVM(8);
            else if (rem == 1) WAITVM(4);
            else               WAITVM(0);
        }
        __builtin_amdgcn_s_barrier();
        __builtin_amdgcn_sched_barrier(0);
        if (t + 3 < ntile) STAGEKV((t + 3) & 3, tg0 + t + 3);

        const int slot = t & 3;

        // S = Q K^T from staged K tile
        f32x4 sf[4];
        #pragma unroll
        for (int f = 0; f < 4; ++f) {
            f32x4 s = (f32x4){0.f, 0.f, 0.f, 0.f};
            int row = f * 16 + lr;
            bf16x8 kb0 = *(const bf16x8*)&Kt[slot][row][((lg    ) ^ (lr & 7)) * 8];
            bf16x8 kb1 = *(const bf16x8*)&Kt[slot][row][((lg + 4) ^ (lr & 7)) * 8];
            s = MFMA16(qf0, kb0, s);
            s = MFMA16(qf1, kb1, s);
            sf[f] = s;
        }

        // causal mask: only the diagonal block tile (tg == j)
        if (tg == j) {
            #pragma unroll
            for (int f = 0; f < 4; ++f) {
                int kvl = f * 16 + lr;
                #pragma unroll
                for (int r = 0; r < 4; ++r) {
                    int ql = w * 16 + lg * 4 + r;
                    if (kvl > ql) sf[f][r] = -3.0e38f;
                }
            }
        }

        // online softmax (row r lives in 16-lane group lg)
        #pragma unroll
        for (int r = 0; r < 4; ++r) {
            float pmx = fmaxf(fmaxf(sf[0][r], sf[1][r]), fmaxf(sf[2][r], sf[3][r]));
            #pragma unroll
            for (int mm = 1; mm < 16; mm <<= 1) pmx = fmaxf(pmx, __shfl_xor(pmx, mm));
            float mnew = fmaxf(mrow[r], pmx);
            float corr = __expf(mrow[r] - mnew);
            mrow[r] = mnew;
            float rs = 0.f;
            #pragma unroll
            for (int f = 0; f < 4; ++f) {
                float p = __expf(sf[f][r] - mnew);
                sf[f][r] = p;
                rs += p;
            }
            #pragma unroll
            for (int mm = 1; mm < 16; mm <<= 1) rs += __shfl_xor(rs, mm);
            lsum[r] = lsum[r] * corr + rs;
            #pragma unroll
            for (int hf = 0; hf < 4; ++hf) O[hf][r] *= corr;
        }

        // P: C-layout -> wave-private LDS -> A-layout (same-wave)
        #pragma unroll
        for (int f = 0; f < 4; ++f)
            #pragma unroll
            for (int r = 0; r < 4; ++r)
                Ps[w][lg * 4 + r][lr + 16 * f] = f2bf(sf[f][r]);

        bf16x8 pa0 = *(const bf16x8*)&Ps[w][lr][lg * 8];
        bf16x8 pa1 = *(const bf16x8*)&Ps[w][lr][lg * 8 + 32];

        // O += P V from staged V tile
        #pragma unroll
        for (int hf = 0; hf < 4; ++hf) {
            int row = hf * 16 + lr;
            bf16x8 vb0 = *(const bf16x8*)&Vt[slot][row][((lg    ) ^ (lr & 7)) * 8];
            bf16x8 vb1 = *(const bf16x8*)&Vt[slot][row][((lg + 4) ^ (lr & 7)) * 8];
            O[hf] = MFMA16(pa0, vb0, O[hf]);
            O[hf] = MFMA16(pa1, vb1, O[hf]);
        }
    }

    // write partial: pidx = b*288 + prefix(j) + c, prefix(j) = (a+1)(4a+r), j=8a+r
    const int a8 = j >> 3, r8 = j & 7;
    const int pidx = b * 288 + (a8 + 1) * (4 * a8 + r8) + c;
    float* Po = pO + (size_t)pidx * 4096;
    #pragma unroll
    for (int hf = 0; hf < 4; ++hf)
        #pragma unroll
        for (int r = 0; r < 4; ++r)
            Po[(w * 16 + lg * 4 + r) * 64 + lr + 16 * hf] = O[hf][r];
    if (lr == 0) {
        #pragma unroll
        for (int r = 0; r < 4; ++r) {
            pm[pidx * 64 + w * 16 + lg * 4 + r] = mrow[r];
            pl[pidx * 64 + w * 16 + lg * 4 + r] = lsum[r];
        }
    }
    #undef STAGEKV
}

// ---------------------------------------------------------------------------
// Kernel 3: attention phase B — merge chunk partials (exact online-softmax).
// Block = (b, j); thread -> (row, 16-h slice); <=8 chunks.
// ---------------------------------------------------------------------------
__global__ __launch_bounds__(256) void attn_merge(
    const float* __restrict__ pO, const float* __restrict__ pm,
    const float* __restrict__ pl, float* __restrict__ out)
{
    const int bid = blockIdx.x;
    const int b = bid & 3, j = bid >> 2;
    const int nch = (j >> 3) + 1;
    const int a8 = j >> 3, r8 = j & 7;
    const int pbase = b * 288 + (a8 + 1) * (4 * a8 + r8);
    const int tid = threadIdx.x;
    const int row = tid >> 2, hq = (tid & 3) * 16;

    float M = -3.0e38f, L = 0.f;
    f32x4 acc0 = {0,0,0,0}, acc1 = {0,0,0,0}, acc2 = {0,0,0,0}, acc3 = {0,0,0,0};
    for (int cc = 0; cc < nch; ++cc) {
        int pidx = pbase + cc;
        float mc = pm[pidx * 64 + row];
        float lc = pl[pidx * 64 + row];
        const f32x4* po = (const f32x4*)(pO + (size_t)pidx * 4096 + row * 64 + hq);
        float Mn = fmaxf(M, mc);
        float sO = __expf(M - Mn), sN = __expf(mc - Mn);
        L = L * sO + lc * sN;
        acc0 = acc0 * sO + po[0] * sN;
        acc1 = acc1 * sO + po[1] * sN;
        acc2 = acc2 * sO + po[2] * sN;
        acc3 = acc3 * sO + po[3] * sN;
        M = Mn;
    }
    float inv = 1.f / L;
    float* op = out + ((size_t)b * NS + (size_t)j * 64 + row) * NH + hq;
    *(f32x4*)(op + 0)  = acc0 * inv;
    *(f32x4*)(op + 4)  = acc1 * inv;
    *(f32x4*)(op + 8)  = acc2 * inv;
    *(f32x4*)(op + 12) = acc3 * inv;
}

extern "C" void kernel_launch(void* const* d_in, const int* in_sizes, int n_in,
                              void* d_out, int out_size, void* d_ws, size_t ws_size,
                              hipStream_t stream)
{
    const float* x  = (const float*)d_in[0];
    const float* Wq = (const float*)d_in[1];
    const float* Wk = (const float*)d_in[2];
    const float* Wv = (const float*)d_in[3];
    float* out = (float*)d_out;

    const size_t n = (size_t)NB * NS * NH;            // 1,048,576 elements
    unsigned short* qb_ = (unsigned short*)d_ws;      // 2 MB
    unsigned short* kb_ = qb_ + n;                    // 2 MB
    unsigned short* vT  = kb_ + n;                    // 2 MB (layout [b][h][s])
    unsigned short* wT  = vT + n;                     // 384 KB (layout [192][1024])
    float* pO  = (float*)(wT + 192 * 1024);           // 1152 x 4096 f32 = 18.9 MB
    float* pm_ = pO + (size_t)1152 * 4096;            // 1152 x 64 f32
    float* pl_ = pm_ + 1152 * 64;                     // 1152 x 64 f32

    wconv<<<dim3(192), dim3(256), 0, stream>>>(Wq, Wk, Wv, wT);
    qkv_proj<<<dim3(512), dim3(256), 0, stream>>>(x, wT, qb_, kb_, vT);
    attn_part<<<dim3(2048), dim3(256), 0, stream>>>(qb_, kb_, vT, pO, pm_, pl_);
    attn_merge<<<dim3(256), dim3(256), 0, stream>>>(pO, pm_, pl_, out);
}

// Round 6
// 71.446 us; speedup vs baseline: 1.2325x; 1.2325x over previous
//
#include <hip/hip_runtime.h>

typedef __attribute__((ext_vector_type(8))) short bf16x8;
typedef __attribute__((ext_vector_type(4))) float f32x4;

#define MFMA16(A, Bv, C) __builtin_amdgcn_mfma_f32_16x16x32_bf16((A), (Bv), (C), 0, 0, 0)
#define WAITVM(N) asm volatile("s_waitcnt vmcnt(" #N ")" ::: "memory")

static constexpr int NB = 4, NS = 4096, ND = 1024, NH = 64;

__device__ __forceinline__ unsigned short f2bf(float f) {
    union { float f; unsigned int u; } x; x.f = f;
    unsigned int r = x.u + 0x7fffu + ((x.u >> 16) & 1u);
    return (unsigned short)(r >> 16);
}

// async global->LDS, 16B per lane; LDS dest = wave-uniform base + lane*16
__device__ __forceinline__ void gload_lds16(const void* g, void* l) {
    __builtin_amdgcn_global_load_lds((const __attribute__((address_space(1))) void*)g,
                                     (__attribute__((address_space(3))) void*)l, 16, 0, 0);
}

// ---------------------------------------------------------------------------
// Kernel 0: W[D][H] fp32 -> wT[m*64+n][k] bf16  (192 x 1024, 384 KB, L2-hot)
// ---------------------------------------------------------------------------
__global__ __launch_bounds__(256) void wconv(
    const float* __restrict__ Wq, const float* __restrict__ Wk,
    const float* __restrict__ Wv, unsigned short* __restrict__ wT)
{
    int mn = blockIdx.x;                 // 0..191 = m*64 + n
    int m = mn >> 6, n = mn & 63;
    const float* W = (m == 0) ? Wq : (m == 1) ? Wk : Wv;
    unsigned short* dst = wT + (size_t)mn * ND;
    for (int k = threadIdx.x; k < ND; k += 256)
        dst[k] = f2bf(W[(size_t)k * NH + n]);
}

// ---------------------------------------------------------------------------
// Kernel 1: QKV projection (unchanged from R5 — ring-4, counted vmcnt).
// ---------------------------------------------------------------------------
__global__ __launch_bounds__(256) void qkv_proj(
    const float* __restrict__ x, const unsigned short* __restrict__ wT,
    unsigned short* __restrict__ qo, unsigned short* __restrict__ ko,
    unsigned short* __restrict__ vt)
{
    __shared__ unsigned short Ws[4][192][32];   // [slot][n-row][k], row = 64B
    __shared__ float Xs[4][32][32];             // [slot][row][k-float], row = 128B
    __shared__ unsigned short Ls[32][72];       // v transpose staging

    const int tid  = threadIdx.x;
    const int lane = tid & 63;
    const int w    = tid >> 6;
    const int lr   = lane & 15;
    const int lg   = lane >> 4;
    const int rf   = w & 1;                     // row-frag
    const int cg   = w >> 1;                    // col half
    const int mbase = blockIdx.x * 32;

    const int srow = lane >> 2;
    const int schk = (lane & 3) ^ (srow & 3);              // pre-swizzled source chunk
    const int xrow = lane >> 3;
    const int xchk = (lane & 7) ^ ((xrow & 3) << 1);       // 32B-granule XOR swizzle

    f32x4 acc[6];                               // [m*2+fi]
    #pragma unroll
    for (int i = 0; i < 6; ++i) acc[i] = (f32x4){0.f, 0.f, 0.f, 0.f};

    #define STAGE(slot, kt)                                                          \
        do {                                                                         \
            _Pragma("unroll")                                                        \
            for (int i_ = 0; i_ < 3; ++i_) {                                         \
                int rbase_ = w * 48 + i_ * 16;                                       \
                const unsigned short* src_ =                                         \
                    wT + (size_t)(rbase_ + srow) * ND + (kt) * 32 + schk * 8;        \
                gload_lds16(src_, &Ws[slot][rbase_][0]);                             \
            }                                                                        \
            {                                                                        \
                const float* xsrc_ =                                                 \
                    x + (size_t)(mbase + w * 8 + xrow) * ND + (kt) * 32 + xchk * 4;  \
                gload_lds16(xsrc_, &Xs[slot][w * 8][0]);                             \
            }                                                                        \
        } while (0)

    STAGE(0, 0);
    STAGE(1, 1);
    STAGE(2, 2);

    const int xg = (lg ^ (lr & 3)) * 8;         // swizzled float offset for x read
    for (int kt = 0; kt < 32; ++kt) {
        __builtin_amdgcn_sched_barrier(0);
        if (kt < 30)       WAITVM(8);
        else if (kt == 30) WAITVM(4);
        else               WAITVM(0);
        __builtin_amdgcn_s_barrier();
        __builtin_amdgcn_sched_barrier(0);
        if (kt + 3 < 32) STAGE((kt + 3) & 3, kt + 3);

        const int slot = kt & 3;
        float4 u0 = *(const float4*)&Xs[slot][rf * 16 + lr][xg];
        float4 u1 = *(const float4*)&Xs[slot][rf * 16 + lr][xg + 4];
        bf16x8 a;
        a[0] = (short)f2bf(u0.x); a[1] = (short)f2bf(u0.y);
        a[2] = (short)f2bf(u0.z); a[3] = (short)f2bf(u0.w);
        a[4] = (short)f2bf(u1.x); a[5] = (short)f2bf(u1.y);
        a[6] = (short)f2bf(u1.z); a[7] = (short)f2bf(u1.w);

        #pragma unroll
        for (int m = 0; m < 3; ++m)
            #pragma unroll
            for (int fi = 0; fi < 2; ++fi) {
                int row = m * 64 + (cg * 2 + fi) * 16 + lr;
                bf16x8 bfr = *(const bf16x8*)&Ws[slot][row][((lg ^ (lr & 3))) * 8];
                acc[m * 2 + fi] = MFMA16(a, bfr, acc[m * 2 + fi]);
            }
    }

    #pragma unroll
    for (int fi = 0; fi < 2; ++fi)
        #pragma unroll
        for (int r = 0; r < 4; ++r) {
            int srw = lg * 4 + r;                 // C/D: row=(lane>>4)*4+reg
            int col = (cg * 2 + fi) * 16 + lr;    //      col=lane&15
            size_t grow = (size_t)(mbase + rf * 16 + srw);
            qo[grow * NH + col] = f2bf(acc[fi][r] * 0.125f);
            ko[grow * NH + col] = f2bf(acc[2 + fi][r]);
            Ls[rf * 16 + srw][col] = f2bf(acc[4 + fi][r]);
        }
    __syncthreads();
    {   // transpose 32 s x 64 h: thread -> (h, 8-s strip)
        int h  = tid >> 2;
        int so = (tid & 3) * 8;
        unsigned short tmp[8];
        #pragma unroll
        for (int jj = 0; jj < 8; ++jj) tmp[jj] = Ls[so + jj][h];
        int b_ = mbase >> 12;
        int sb = (mbase & (NS - 1)) + so;
        unsigned short* dst = vt + ((size_t)(b_ * NH + h)) * NS + sb;
        bf16x8 v0;
        #pragma unroll
        for (int jj = 0; jj < 8; ++jj) v0[jj] = (short)tmp[jj];
        *(bf16x8*)dst = v0;
    }
    #undef STAGE
}

// ---------------------------------------------------------------------------
// Kernel 2: attention phase A — R4 2-slot staging + SWAPPED-OPERAND math.
// S^T = mfma(K, Q): C col=lane&15=q, row=(lane>>4)*4+reg=kv  -> each lane owns
// one q-row with 16 S values in-register. Softmax: in-register reduce + 2
// shfl_xor (16,32). O^T = mfma(V^T, P^T): accumulator lands at q=lane&15 too,
// so corr is a per-lane scalar and the partial write is 4x f32x4.
// ---------------------------------------------------------------------------
__global__ __launch_bounds__(256) void attn_part(
    const unsigned short* __restrict__ q, const unsigned short* __restrict__ k,
    const unsigned short* __restrict__ vt, float* __restrict__ pO,
    float* __restrict__ pm, float* __restrict__ pl)
{
    __shared__ unsigned short Kt[2][64][64];   // [buf][kv][d], swizzled chunks
    __shared__ unsigned short Vt[2][64][64];   // [buf][h][kv], swizzled chunks
    __shared__ unsigned short Ps[4][16][72];   // [wave][q][kv]

    const int bid = blockIdx.x;
    const int b = bid & 3;
    const int j = (bid >> 2) & 63;
    const int c = bid >> 8;                    // 0..7
    if (c > (j >> 3)) return;                  // dead block (beyond causal extent)
    const int ntile = (j + 1 - c * 8 < 8) ? (j + 1 - c * 8) : 8;
    const int tg0 = c * 8;

    const int tid  = threadIdx.x;
    const int lane = tid & 63;
    const int w    = tid >> 6;
    const int lr   = lane & 15;
    const int lg   = lane >> 4;
    const size_t bq = (size_t)b * NS;
    const int qb = j * 64;

    const int srow = lane >> 3;
    const int schk = (lane & 7) ^ srow;        // pre-swizzled source chunk

    #define STAGEKV(buf, tg)                                                          \
        do {                                                                          \
            int kvb_ = (tg) * 64;                                                     \
            if (w < 2) {                                                              \
                _Pragma("unroll")                                                     \
                for (int i_ = 0; i_ < 4; ++i_) {                                      \
                    int rb_ = w * 32 + i_ * 8;                                        \
                    const unsigned short* src_ =                                      \
                        k + (bq + kvb_ + rb_ + srow) * NH + schk * 8;                 \
                    gload_lds16(src_, &Kt[buf][rb_][0]);                              \
                }                                                                     \
            } else {                                                                  \
                _Pragma("unroll")                                                     \
                for (int i_ = 0; i_ < 4; ++i_) {                                      \
                    int rb_ = (w - 2) * 32 + i_ * 8;                                  \
                    const unsigned short* src_ =                                      \
                        vt + ((size_t)(b * NH + rb_ + srow)) * NS + kvb_ + schk * 8;  \
                    gload_lds16(src_, &Vt[buf][rb_][0]);                              \
                }                                                                     \
            }                                                                         \
        } while (0)

    // Q frags: rows qb + w*16 + lr, used as B-operand (same lane layout as A)
    bf16x8 qf0, qf1;
    {
        const unsigned short* qp = q + (bq + qb + w * 16 + lr) * NH + lg * 8;
        qf0 = *(const bf16x8*)qp;
        qf1 = *(const bf16x8*)(qp + 32);
    }

    f32x4 O[4];                                // O^T: [hf] -> h=hf*16+lg*4+r, q=lr
    #pragma unroll
    for (int i = 0; i < 4; ++i) O[i] = (f32x4){0.f, 0.f, 0.f, 0.f};
    float mrow = -3.0e38f, lsum = 0.f;         // per-lane: q-row = w*16+lr

    STAGEKV(0, tg0);
    __syncthreads();

    int cur = 0;
    for (int t = 0; t < ntile; ++t) {
        const int tg = tg0 + t;
        // issue next stage first (dummy re-stage of tg0 on last iter keeps code uniform)
        STAGEKV(cur ^ 1, (t + 1 < ntile) ? tg + 1 : tg0);

        // S^T = K Q^T: sf[f][r] = S[kv = f*16+lg*4+r][q = w*16+lr]
        f32x4 sf[4];
        #pragma unroll
        for (int f = 0; f < 4; ++f) {
            f32x4 s = (f32x4){0.f, 0.f, 0.f, 0.f};
            int row = f * 16 + lr;
            bf16x8 kb0 = *(const bf16x8*)&Kt[cur][row][((lg    ) ^ (lr & 7)) * 8];
            bf16x8 kb1 = *(const bf16x8*)&Kt[cur][row][((lg + 4) ^ (lr & 7)) * 8];
            s = MFMA16(kb0, qf0, s);
            s = MFMA16(kb1, qf1, s);
            sf[f] = s;
        }

        // causal mask: only the diagonal block tile (tg == j)
        if (tg == j) {
            #pragma unroll
            for (int f = 0; f < 4; ++f) {
                #pragma unroll
                for (int r = 0; r < 4; ++r) {
                    int kvl = f * 16 + lg * 4 + r;
                    int ql  = w * 16 + lr;
                    if (kvl > ql) sf[f][r] = -3.0e38f;
                }
            }
        }

        // softmax: lane-local 16-value reduce + 2 shfl (lanes lr, lr+16, +32, +48)
        float pmx = fmaxf(fmaxf(fmaxf(sf[0][0], sf[0][1]), fmaxf(sf[0][2], sf[0][3])),
                          fmaxf(fmaxf(sf[1][0], sf[1][1]), fmaxf(sf[1][2], sf[1][3])));
        float pmx2 = fmaxf(fmaxf(fmaxf(sf[2][0], sf[2][1]), fmaxf(sf[2][2], sf[2][3])),
                           fmaxf(fmaxf(sf[3][0], sf[3][1]), fmaxf(sf[3][2], sf[3][3])));
        pmx = fmaxf(pmx, pmx2);
        pmx = fmaxf(pmx, __shfl_xor(pmx, 16));
        pmx = fmaxf(pmx, __shfl_xor(pmx, 32));
        float mnew = fmaxf(mrow, pmx);
        float corr = __expf(mrow - mnew);
        mrow = mnew;
        float rs = 0.f;
        #pragma unroll
        for (int f = 0; f < 4; ++f)
            #pragma unroll
            for (int r = 0; r < 4; ++r) {
                float p = __expf(sf[f][r] - mnew);
                sf[f][r] = p;
                rs += p;
            }
        rs += __shfl_xor(rs, 16);
        rs += __shfl_xor(rs, 32);
        lsum = lsum * corr + rs;
        #pragma unroll
        for (int hf = 0; hf < 4; ++hf) O[hf] *= corr;

        // P^T: lane holds P[q=lr][kv=f*16+lg*4+r] -> Ps[w][q][kv] -> B-frag
        #pragma unroll
        for (int f = 0; f < 4; ++f)
            #pragma unroll
            for (int r = 0; r < 4; ++r)
                Ps[w][lr][f * 16 + lg * 4 + r] = f2bf(sf[f][r]);

        bf16x8 pb0 = *(const bf16x8*)&Ps[w][lr][lg * 8];        // kv 0..31
        bf16x8 pb1 = *(const bf16x8*)&Ps[w][lr][32 + lg * 8];   // kv 32..63

        // O^T += V^T P^T  (A = V^T rows h, B = P^T cols q)
        #pragma unroll
        for (int hf = 0; hf < 4; ++hf) {
            int row = hf * 16 + lr;
            bf16x8 vb0 = *(const bf16x8*)&Vt[cur][row][((lg    ) ^ (lr & 7)) * 8];
            bf16x8 vb1 = *(const bf16x8*)&Vt[cur][row][((lg + 4) ^ (lr & 7)) * 8];
            O[hf] = MFMA16(vb0, pb0, O[hf]);
            O[hf] = MFMA16(vb1, pb1, O[hf]);
        }

        __syncthreads();   // stage(t+1) landed + all reads of cur done
        cur ^= 1;
    }

    // write partial: lane owns q-row w*16+lr; O[hf][r] -> h = hf*16 + lg*4 + r
    const int a8 = j >> 3, r8 = j & 7;
    const int pidx = b * 288 + (a8 + 1) * (4 * a8 + r8) + c;
    float* Po = pO + (size_t)pidx * 4096;
    #pragma unroll
    for (int hf = 0; hf < 4; ++hf)
        *(f32x4*)&Po[(w * 16 + lr) * 64 + hf * 16 + lg * 4] = O[hf];
    if (lane < 16) {
        pm[pidx * 64 + w * 16 + lane] = mrow;
        pl[pidx * 64 + w * 16 + lane] = lsum;
    }
    #undef STAGEKV
}

// ---------------------------------------------------------------------------
// Kernel 3: attention phase B — merge chunk partials (exact online-softmax).
// Block = (b, j); thread -> (row, 16-h slice); <=8 chunks.
// ---------------------------------------------------------------------------
__global__ __launch_bounds__(256) void attn_merge(
    const float* __restrict__ pO, const float* __restrict__ pm,
    const float* __restrict__ pl, float* __restrict__ out)
{
    const int bid = blockIdx.x;
    const int b = bid & 3, j = bid >> 2;
    const int nch = (j >> 3) + 1;
    const int a8 = j >> 3, r8 = j & 7;
    const int pbase = b * 288 + (a8 + 1) * (4 * a8 + r8);
    const int tid = threadIdx.x;
    const int row = tid >> 2, hq = (tid & 3) * 16;

    float M = -3.0e38f, L = 0.f;
    f32x4 acc0 = {0,0,0,0}, acc1 = {0,0,0,0}, acc2 = {0,0,0,0}, acc3 = {0,0,0,0};
    for (int cc = 0; cc < nch; ++cc) {
        int pidx = pbase + cc;
        float mc = pm[pidx * 64 + row];
        float lc = pl[pidx * 64 + row];
        const f32x4* po = (const f32x4*)(pO + (size_t)pidx * 4096 + row * 64 + hq);
        float Mn = fmaxf(M, mc);
        float sO = __expf(M - Mn), sN = __expf(mc - Mn);
        L = L * sO + lc * sN;
        acc0 = acc0 * sO + po[0] * sN;
        acc1 = acc1 * sO + po[1] * sN;
        acc2 = acc2 * sO + po[2] * sN;
        acc3 = acc3 * sO + po[3] * sN;
        M = Mn;
    }
    float inv = 1.f / L;
    float* op = out + ((size_t)b * NS + (size_t)j * 64 + row) * NH + hq;
    *(f32x4*)(op + 0)  = acc0 * inv;
    *(f32x4*)(op + 4)  = acc1 * inv;
    *(f32x4*)(op + 8)  = acc2 * inv;
    *(f32x4*)(op + 12) = acc3 * inv;
}

extern "C" void kernel_launch(void* const* d_in, const int* in_sizes, int n_in,
                              void* d_out, int out_size, void* d_ws, size_t ws_size,
                              hipStream_t stream)
{
    const float* x  = (const float*)d_in[0];
    const float* Wq = (const float*)d_in[1];
    const float* Wk = (const float*)d_in[2];
    const float* Wv = (const float*)d_in[3];
    float* out = (float*)d_out;

    const size_t n = (size_t)NB * NS * NH;            // 1,048,576 elements
    unsigned short* qb_ = (unsigned short*)d_ws;      // 2 MB
    unsigned short* kb_ = qb_ + n;                    // 2 MB
    unsigned short* vT  = kb_ + n;                    // 2 MB (layout [b][h][s])
    unsigned short* wT  = vT + n;                     // 384 KB (layout [192][1024])
    float* pO  = (float*)(wT + 192 * 1024);           // 1152 x 4096 f32 = 18.9 MB
    float* pm_ = pO + (size_t)1152 * 4096;            // 1152 x 64 f32
    float* pl_ = pm_ + 1152 * 64;                     // 1152 x 64 f32

    wconv<<<dim3(192), dim3(256), 0, stream>>>(Wq, Wk, Wv, wT);
    qkv_proj<<<dim3(512), dim3(256), 0, stream>>>(x, wT, qb_, kb_, vT);
    attn_part<<<dim3(2048), dim3(256), 0, stream>>>(qb_, kb_, vT, pO, pm_, pl_);
    attn_merge<<<dim3(256), dim3(256), 0, stream>>>(pO, pm_, pl_, out);
}

// Round 7
// 68.905 us; speedup vs baseline: 1.2779x; 1.0369x over previous
//
#include <hip/hip_runtime.h>

typedef __attribute__((ext_vector_type(8))) short bf16x8;
typedef __attribute__((ext_vector_type(4))) float f32x4;

#define MFMA16(A, Bv, C) __builtin_amdgcn_mfma_f32_16x16x32_bf16((A), (Bv), (C), 0, 0, 0)
#define WAITVM(N) asm volatile("s_waitcnt vmcnt(" #N ")" ::: "memory")

static constexpr int NB = 4, NS = 4096, ND = 1024, NH = 64;

__device__ __forceinline__ unsigned short f2bf(float f) {
    union { float f; unsigned int u; } x; x.f = f;
    unsigned int r = x.u + 0x7fffu + ((x.u >> 16) & 1u);
    return (unsigned short)(r >> 16);
}

// async global->LDS, 16B per lane; LDS dest = wave-uniform base + lane*16
__device__ __forceinline__ void gload_lds16(const void* g, void* l) {
    __builtin_amdgcn_global_load_lds((const __attribute__((address_space(1))) void*)g,
                                     (__attribute__((address_space(3))) void*)l, 16, 0, 0);
}

// ---------------------------------------------------------------------------
// Kernel 0: W[D][H] fp32 -> wT[m*64+n][k] bf16  (192 x 1024, 384 KB, L2-hot)
// ---------------------------------------------------------------------------
__global__ __launch_bounds__(256) void wconv(
    const float* __restrict__ Wq, const float* __restrict__ Wk,
    const float* __restrict__ Wv, unsigned short* __restrict__ wT)
{
    int mn = blockIdx.x;                 // 0..191 = m*64 + n
    int m = mn >> 6, n = mn & 63;
    const float* W = (m == 0) ? Wq : (m == 1) ? Wk : Wv;
    unsigned short* dst = wT + (size_t)mn * ND;
    for (int k = threadIdx.x; k < ND; k += 256)
        dst[k] = f2bf(W[(size_t)k * NH + n]);
}

// ---------------------------------------------------------------------------
// Kernel 1: QKV projection, work-dense phases.
// 256 blocks (1/CU) x 512 threads (8 waves as 2M x 4N). M-tile 64, N full 192,
// BK = 64 -> 16 macro-steps, ONE barrier each, 96 MFMA + ~150KB LDS per step
// per block (4x the work/barrier of R6). Ring-3 LDS slots (W 24KB + x fp32
// 16KB each), depth-2 prefetch, counted vmcnt(5) (all VMEM = global_load_lds,
// 5/wave/step -> order-insensitive). 8-row-period XOR swizzle on both W and x
// (stage source pre-swizzled, read applies same map; rule #21).
// ---------------------------------------------------------------------------
__global__ __launch_bounds__(512) void qkv_proj(
    const float* __restrict__ x, const unsigned short* __restrict__ wT,
    unsigned short* __restrict__ qo, unsigned short* __restrict__ ko,
    unsigned short* __restrict__ vt)
{
    __shared__ unsigned short Ws[3][192][64];   // [slot][n][k] bf16, swizzled chunks
    __shared__ float Xs[3][64][64];             // [slot][m][k] fp32, swizzled chunks
    __shared__ unsigned short Ls[64][72];       // v transpose staging

    const int tid  = threadIdx.x;               // 0..511
    const int lane = tid & 63;
    const int w    = tid >> 6;                  // 0..7
    const int lr   = lane & 15;
    const int lg   = lane >> 4;
    const int mg   = w >> 2;                    // M half (rows mg*32..+32)
    const int cg   = w & 3;                     // N quarter (cols cg*48..+48)
    const int mbase = blockIdx.x * 64;

    // W stage: instr = 8 rows x 128B; lane -> row lane>>3, chunk lane&7.
    // LDS[r][c] must hold src[r][c ^ (r&7)] -> source chunk = (lane&7)^(lane>>3).
    const int wr8 = lane >> 3;
    const int wck = (lane & 7) ^ wr8;
    // x stage: instr = 4 rows x 256B; lane -> row lane>>4, chunk lane&15.
    // LDS[r][c] holds src[r][c ^ ((r&7)<<1)].
    const int xr4 = lane >> 4;
    const int xck = lane & 15;

    f32x4 acc[6];                               // [a*3+f]
    #pragma unroll
    for (int i = 0; i < 6; ++i) acc[i] = (f32x4){0.f, 0.f, 0.f, 0.f};

    // 5 gload_lds per wave per step: 3 W (rows w*24..+24) + 2 x (rows w*8..+8)
    #define STAGE(slot, kb)                                                           \
        do {                                                                          \
            _Pragma("unroll")                                                         \
            for (int i_ = 0; i_ < 3; ++i_) {                                          \
                int rb_ = w * 24 + i_ * 8;                                            \
                gload_lds16(wT + (size_t)(rb_ + wr8) * ND + (kb) + wck * 8,           \
                            &Ws[slot][rb_][0]);                                       \
            }                                                                         \
            _Pragma("unroll")                                                         \
            for (int j_ = 0; j_ < 2; ++j_) {                                          \
                int rb_ = w * 8 + j_ * 4;                                             \
                int r7_ = (rb_ + xr4) & 7;                                            \
                gload_lds16(x + (size_t)(mbase + rb_ + xr4) * ND + (kb)               \
                                + (xck ^ (r7_ << 1)) * 4,                             \
                            &Xs[slot][rb_][0]);                                       \
            }                                                                         \
        } while (0)

    // prologue: prefetch steps 0,1
    STAGE(0, 0);
    STAGE(1, 64);

    for (int kt = 0; kt < 16; ++kt) {
        __builtin_amdgcn_sched_barrier(0);
        if (kt < 15) WAITVM(5);                 // slot kt landed; slot kt+1 in flight
        else         WAITVM(0);
        __builtin_amdgcn_s_barrier();
        __builtin_amdgcn_sched_barrier(0);
        if (kt + 2 < 16) STAGE((kt + 2) % 3, (kt + 2) * 64);
        __builtin_amdgcn_sched_barrier(0);

        const int slot = kt % 3;
        #pragma unroll
        for (int sub = 0; sub < 2; ++sub) {
            bf16x8 bfr[3];
            #pragma unroll
            for (int f = 0; f < 3; ++f) {
                int row = cg * 48 + f * 16 + lr;
                bfr[f] = *(const bf16x8*)&Ws[slot][row][(((sub << 2) | lg) ^ (lr & 7)) * 8];
            }
            #pragma unroll
            for (int a = 0; a < 2; ++a) {
                int row = mg * 32 + a * 16 + lr;
                const float* xp =
                    &Xs[slot][row][((((sub << 3) | (lg << 1)) ^ ((lr & 7) << 1))) * 4];
                float4 u0 = *(const float4*)xp;
                float4 u1 = *(const float4*)(xp + 4);
                bf16x8 af;
                af[0] = (short)f2bf(u0.x); af[1] = (short)f2bf(u0.y);
                af[2] = (short)f2bf(u0.z); af[3] = (short)f2bf(u0.w);
                af[4] = (short)f2bf(u1.x); af[5] = (short)f2bf(u1.y);
                af[6] = (short)f2bf(u1.z); af[7] = (short)f2bf(u1.w);
                #pragma unroll
                for (int f = 0; f < 3; ++f)
                    acc[a * 3 + f] = MFMA16(af, bfr[f], acc[a * 3 + f]);
            }
        }
    }

    // epilogue: frag (cg,f) covers n-block b16 = cg*3+f (16 cols, never crosses
    // a q/k/v boundary). q scaled by 0.125; v staged to Ls for transpose.
    #pragma unroll
    for (int a = 0; a < 2; ++a)
        #pragma unroll
        for (int f = 0; f < 3; ++f) {
            int b16 = cg * 3 + f;
            int sel = b16 >> 2;
            int col = (b16 & 3) * 16 + lr;
            #pragma unroll
            for (int rr = 0; rr < 4; ++rr) {
                int mrow = mg * 32 + a * 16 + lg * 4 + rr;   // C/D: row=(lane>>4)*4+reg
                float v = acc[a * 3 + f][rr];
                if (sel == 0)
                    qo[(size_t)(mbase + mrow) * NH + col] = f2bf(v * 0.125f);
                else if (sel == 1)
                    ko[(size_t)(mbase + mrow) * NH + col] = f2bf(v);
                else
                    Ls[mrow][col] = f2bf(v);
            }
        }
    __syncthreads();
    {   // transpose 64 s x 64 h: thread -> (h = tid>>3, 8-s strip)
        int h  = tid >> 3;
        int s8 = (tid & 7) * 8;
        unsigned short tmp[8];
        #pragma unroll
        for (int jj = 0; jj < 8; ++jj) tmp[jj] = Ls[s8 + jj][h];
        int b_ = mbase >> 12;
        int sb = (mbase & (NS - 1)) + s8;
        unsigned short* dst = vt + ((size_t)(b_ * NH + h)) * NS + sb;
        bf16x8 v0;
        #pragma unroll
        for (int jj = 0; jj < 8; ++jj) v0[jj] = (short)tmp[jj];
        *(bf16x8*)dst = v0;
    }
    #undef STAGE
}

// ---------------------------------------------------------------------------
// Kernel 2: attention phase A — 2-slot staging + swapped-operand math
// (unchanged from R6).
// ---------------------------------------------------------------------------
__global__ __launch_bounds__(256) void attn_part(
    const unsigned short* __restrict__ q, const unsigned short* __restrict__ k,
    const unsigned short* __restrict__ vt, float* __restrict__ pO,
    float* __restrict__ pm, float* __restrict__ pl)
{
    __shared__ unsigned short Kt[2][64][64];   // [buf][kv][d], swizzled chunks
    __shared__ unsigned short Vt[2][64][64];   // [buf][h][kv], swizzled chunks
    __shared__ unsigned short Ps[4][16][72];   // [wave][q][kv]

    const int bid = blockIdx.x;
    const int b = bid & 3;
    const int j = (bid >> 2) & 63;
    const int c = bid >> 8;                    // 0..7
    if (c > (j >> 3)) return;                  // dead block (beyond causal extent)
    const int ntile = (j + 1 - c * 8 < 8) ? (j + 1 - c * 8) : 8;
    const int tg0 = c * 8;

    const int tid  = threadIdx.x;
    const int lane = tid & 63;
    const int w    = tid >> 6;
    const int lr   = lane & 15;
    const int lg   = lane >> 4;
    const size_t bq = (size_t)b * NS;
    const int qb = j * 64;

    const int srow = lane >> 3;
    const int schk = (lane & 7) ^ srow;        // pre-swizzled source chunk

    #define STAGEKV(buf, tg)                                                          \
        do {                                                                          \
            int kvb_ = (tg) * 64;                                                     \
            if (w < 2) {                                                              \
                _Pragma("unroll")                                                     \
                for (int i_ = 0; i_ < 4; ++i_) {                                      \
                    int rb_ = w * 32 + i_ * 8;                                        \
                    const unsigned short* src_ =                                      \
                        k + (bq + kvb_ + rb_ + srow) * NH + schk * 8;                 \
                    gload_lds16(src_, &Kt[buf][rb_][0]);                              \
                }                                                                     \
            } else {                                                                  \
                _Pragma("unroll")                                                     \
                for (int i_ = 0; i_ < 4; ++i_) {                                      \
                    int rb_ = (w - 2) * 32 + i_ * 8;                                  \
                    const unsigned short* src_ =                                      \
                        vt + ((size_t)(b * NH + rb_ + srow)) * NS + kvb_ + schk * 8;  \
                    gload_lds16(src_, &Vt[buf][rb_][0]);                              \
                }                                                                     \
            }                                                                         \
        } while (0)

    // Q frags: rows qb + w*16 + lr, used as B-operand
    bf16x8 qf0, qf1;
    {
        const unsigned short* qp = q + (bq + qb + w * 16 + lr) * NH + lg * 8;
        qf0 = *(const bf16x8*)qp;
        qf1 = *(const bf16x8*)(qp + 32);
    }

    f32x4 O[4];                                // O^T: [hf] -> h=hf*16+lg*4+r, q=lr
    #pragma unroll
    for (int i = 0; i < 4; ++i) O[i] = (f32x4){0.f, 0.f, 0.f, 0.f};
    float mrow = -3.0e38f, lsum = 0.f;         // per-lane: q-row = w*16+lr

    STAGEKV(0, tg0);
    __syncthreads();

    int cur = 0;
    for (int t = 0; t < ntile; ++t) {
        const int tg = tg0 + t;
        STAGEKV(cur ^ 1, (t + 1 < ntile) ? tg + 1 : tg0);

        // S^T = K Q^T: sf[f][r] = S[kv = f*16+lg*4+r][q = w*16+lr]
        f32x4 sf[4];
        #pragma unroll
        for (int f = 0; f < 4; ++f) {
            f32x4 s = (f32x4){0.f, 0.f, 0.f, 0.f};
            int row = f * 16 + lr;
            bf16x8 kb0 = *(const bf16x8*)&Kt[cur][row][((lg    ) ^ (lr & 7)) * 8];
            bf16x8 kb1 = *(const bf16x8*)&Kt[cur][row][((lg + 4) ^ (lr & 7)) * 8];
            s = MFMA16(kb0, qf0, s);
            s = MFMA16(kb1, qf1, s);
            sf[f] = s;
        }

        if (tg == j) {
            #pragma unroll
            for (int f = 0; f < 4; ++f)
                #pragma unroll
                for (int r = 0; r < 4; ++r) {
                    int kvl = f * 16 + lg * 4 + r;
                    int ql  = w * 16 + lr;
                    if (kvl > ql) sf[f][r] = -3.0e38f;
                }
        }

        // softmax: lane-local 16-value reduce + 2 shfl
        float pmx = fmaxf(fmaxf(fmaxf(sf[0][0], sf[0][1]), fmaxf(sf[0][2], sf[0][3])),
                          fmaxf(fmaxf(sf[1][0], sf[1][1]), fmaxf(sf[1][2], sf[1][3])));
        float pmx2 = fmaxf(fmaxf(fmaxf(sf[2][0], sf[2][1]), fmaxf(sf[2][2], sf[2][3])),
                           fmaxf(fmaxf(sf[3][0], sf[3][1]), fmaxf(sf[3][2], sf[3][3])));
        pmx = fmaxf(pmx, pmx2);
        pmx = fmaxf(pmx, __shfl_xor(pmx, 16));
        pmx = fmaxf(pmx, __shfl_xor(pmx, 32));
        float mnew = fmaxf(mrow, pmx);
        float corr = __expf(mrow - mnew);
        mrow = mnew;
        float rs = 0.f;
        #pragma unroll
        for (int f = 0; f < 4; ++f)
            #pragma unroll
            for (int r = 0; r < 4; ++r) {
                float p = __expf(sf[f][r] - mnew);
                sf[f][r] = p;
                rs += p;
            }
        rs += __shfl_xor(rs, 16);
        rs += __shfl_xor(rs, 32);
        lsum = lsum * corr + rs;
        #pragma unroll
        for (int hf = 0; hf < 4; ++hf) O[hf] *= corr;

        // P^T via wave-private LDS
        #pragma unroll
        for (int f = 0; f < 4; ++f)
            #pragma unroll
            for (int r = 0; r < 4; ++r)
                Ps[w][lr][f * 16 + lg * 4 + r] = f2bf(sf[f][r]);

        bf16x8 pb0 = *(const bf16x8*)&Ps[w][lr][lg * 8];
        bf16x8 pb1 = *(const bf16x8*)&Ps[w][lr][32 + lg * 8];

        // O^T += V^T P^T
        #pragma unroll
        for (int hf = 0; hf < 4; ++hf) {
            int row = hf * 16 + lr;
            bf16x8 vb0 = *(const bf16x8*)&Vt[cur][row][((lg    ) ^ (lr & 7)) * 8];
            bf16x8 vb1 = *(const bf16x8*)&Vt[cur][row][((lg + 4) ^ (lr & 7)) * 8];
            O[hf] = MFMA16(vb0, pb0, O[hf]);
            O[hf] = MFMA16(vb1, pb1, O[hf]);
        }

        __syncthreads();
        cur ^= 1;
    }

    const int a8 = j >> 3, r8 = j & 7;
    const int pidx = b * 288 + (a8 + 1) * (4 * a8 + r8) + c;
    float* Po = pO + (size_t)pidx * 4096;
    #pragma unroll
    for (int hf = 0; hf < 4; ++hf)
        *(f32x4*)&Po[(w * 16 + lr) * 64 + hf * 16 + lg * 4] = O[hf];
    if (lane < 16) {
        pm[pidx * 64 + w * 16 + lane] = mrow;
        pl[pidx * 64 + w * 16 + lane] = lsum;
    }
    #undef STAGEKV
}

// ---------------------------------------------------------------------------
// Kernel 3: attention phase B — merge chunk partials (unchanged).
// ---------------------------------------------------------------------------
__global__ __launch_bounds__(256) void attn_merge(
    const float* __restrict__ pO, const float* __restrict__ pm,
    const float* __restrict__ pl, float* __restrict__ out)
{
    const int bid = blockIdx.x;
    const int b = bid & 3, j = bid >> 2;
    const int nch = (j >> 3) + 1;
    const int a8 = j >> 3, r8 = j & 7;
    const int pbase = b * 288 + (a8 + 1) * (4 * a8 + r8);
    const int tid = threadIdx.x;
    const int row = tid >> 2, hq = (tid & 3) * 16;

    float M = -3.0e38f, L = 0.f;
    f32x4 acc0 = {0,0,0,0}, acc1 = {0,0,0,0}, acc2 = {0,0,0,0}, acc3 = {0,0,0,0};
    for (int cc = 0; cc < nch; ++cc) {
        int pidx = pbase + cc;
        float mc = pm[pidx * 64 + row];
        float lc = pl[pidx * 64 + row];
        const f32x4* po = (const f32x4*)(pO + (size_t)pidx * 4096 + row * 64 + hq);
        float Mn = fmaxf(M, mc);
        float sO = __expf(M - Mn), sN = __expf(mc - Mn);
        L = L * sO + lc * sN;
        acc0 = acc0 * sO + po[0] * sN;
        acc1 = acc1 * sO + po[1] * sN;
        acc2 = acc2 * sO + po[2] * sN;
        acc3 = acc3 * sO + po[3] * sN;
        M = Mn;
    }
    float inv = 1.f / L;
    float* op = out + ((size_t)b * NS + (size_t)j * 64 + row) * NH + hq;
    *(f32x4*)(op + 0)  = acc0 * inv;
    *(f32x4*)(op + 4)  = acc1 * inv;
    *(f32x4*)(op + 8)  = acc2 * inv;
    *(f32x4*)(op + 12) = acc3 * inv;
}

extern "C" void kernel_launch(void* const* d_in, const int* in_sizes, int n_in,
                              void* d_out, int out_size, void* d_ws, size_t ws_size,
                              hipStream_t stream)
{
    const float* x  = (const float*)d_in[0];
    const float* Wq = (const float*)d_in[1];
    const float* Wk = (const float*)d_in[2];
    const float* Wv = (const float*)d_in[3];
    float* out = (float*)d_out;

    const size_t n = (size_t)NB * NS * NH;            // 1,048,576 elements
    unsigned short* qb_ = (unsigned short*)d_ws;      // 2 MB
    unsigned short* kb_ = qb_ + n;                    // 2 MB
    unsigned short* vT  = kb_ + n;                    // 2 MB (layout [b][h][s])
    unsigned short* wT  = vT + n;                     // 384 KB (layout [192][1024])
    float* pO  = (float*)(wT + 192 * 1024);           // 1152 x 4096 f32 = 18.9 MB
    float* pm_ = pO + (size_t)1152 * 4096;            // 1152 x 64 f32
    float* pl_ = pm_ + 1152 * 64;                     // 1152 x 64 f32

    wconv<<<dim3(192), dim3(256), 0, stream>>>(Wq, Wk, Wv, wT);
    qkv_proj<<<dim3(256), dim3(512), 0, stream>>>(x, wT, qb_, kb_, vT);
    attn_part<<<dim3(2048), dim3(256), 0, stream>>>(qb_, kb_, vT, pO, pm_, pl_);
    attn_merge<<<dim3(256), dim3(256), 0, stream>>>(pO, pm_, pl_, out);
}